// Round 1
// baseline (289.273 us; speedup 1.0000x reference)
//
#include <hip/hip_runtime.h>

// SHEmbed, 4-lane cooperative gather, 2-rays-per-thread software pipeline.
// out[i,c] = clip( sum_j B[i,j] * sh_data[y[i],x[i],j,c], 0, 1 ), L=3 (16 basis, 3 ch).
// Cell = 48 floats = 192 B = exactly 3 aligned 64B lines. Lanes 4r..4r+3 handle ray r:
// lane q loads float4 chunks q, q+4, q+8.
//
// Pipeline: thread owns ray A (= gid>>2) and ray B (= A + B/2).
//   - A's 3 chunks -> VGPRs (as before)
//   - B's 3 chunks -> LDS via global_load_lds (no VGPR cost, vmcnt-tracked)
// All 6 gathers are in flight simultaneously -> 2x memory-level parallelism per wave
// at unchanged occupancy (12 KiB LDS/block, VGPR target <=64 via launch_bounds(256,8)).
// B's data is consumed by the SAME wave that issued it -> no barrier, only vmcnt(0).

#define SH_C0   0.28209479177387814f
#define SH_C1   0.48860251190291992f
#define SH_C2a  1.09254843059207907f
#define SH_C2b  0.31539156525252005f
#define SH_C2c  0.54627421529603959f
#define SH_C3a  0.59004358992664352f
#define SH_C3b  2.89061144264055405f
#define SH_C3c  0.45704579946446572f
#define SH_C3d  0.37317633259011546f
#define SH_C3e  1.44530572132027702f

// chunk p covers floats 4p..4p+3 of the cell; float f -> (j=f/3, c=f%3)
#define DO4(v, J0,C0, J1,C1, J2,C2, J3,C3)        \
    s0_ = fmaf(b[J0], (v).x, s0_), (void)0;       \
    DO4_##C0                                       \

// (simple token-paste tricks get unreadable; keep the verified explicit form)
#undef DO4
#define DO4(v, J0,C0, J1,C1, J2,C2, J3,C3)        \
    s##C0 = fmaf(b[J0], (v).x, s##C0);            \
    s##C1 = fmaf(b[J1], (v).y, s##C1);            \
    s##C2 = fmaf(b[J2], (v).z, s##C2);            \
    s##C3 = fmaf(b[J3], (v).w, s##C3);

__device__ __forceinline__ void sh_basis(float dx, float dy, float dz, float b[16])
{
    const float inv = rsqrtf(fmaf(dx, dx, fmaf(dy, dy, dz * dz)));
    const float nx = dx * inv, ny = dy * inv, nz = dz * inv;
    const float x2 = nx * nx, y2 = ny * ny, z2 = nz * nz;
    const float xy = nx * ny, yz = ny * nz, xz = nx * nz;
    b[0]  =  SH_C0;
    b[1]  = -SH_C1 * ny;
    b[2]  =  SH_C1 * nz;
    b[3]  = -SH_C1 * nx;
    b[4]  =  SH_C2a * xy;
    b[5]  = -SH_C2a * yz;
    b[6]  =  SH_C2b * (3.0f * z2 - 1.0f);
    b[7]  = -SH_C2a * xz;
    b[8]  =  SH_C2c * (x2 - y2);
    b[9]  = -SH_C3a * ny * (3.0f * x2 - y2);
    b[10] =  SH_C3b * xy * nz;
    b[11] = -SH_C3c * ny * (5.0f * z2 - 1.0f);
    b[12] =  SH_C3d * nz * (5.0f * z2 - 3.0f);
    b[13] = -SH_C3c * nx * (5.0f * z2 - 1.0f);
    b[14] =  SH_C3e * nz * (x2 - y2);
    b[15] = -SH_C3a * nx * (x2 - 3.0f * y2);
}

__device__ __forceinline__ void sh_accum(int q, const float b[16],
                                         float4 v0, float4 v1, float4 v2,
                                         float& s0o, float& s1o, float& s2o)
{
    float s0 = 0.0f, s1 = 0.0f, s2 = 0.0f;
    switch (q) {
    case 0:
        DO4(v0,  0,0,  0,1,  0,2,  1,0)
        DO4(v1,  5,1,  5,2,  6,0,  6,1)
        DO4(v2, 10,2, 11,0, 11,1, 11,2)
        break;
    case 1:
        DO4(v0,  1,1,  1,2,  2,0,  2,1)
        DO4(v1,  6,2,  7,0,  7,1,  7,2)
        DO4(v2, 12,0, 12,1, 12,2, 13,0)
        break;
    case 2:
        DO4(v0,  2,2,  3,0,  3,1,  3,2)
        DO4(v1,  8,0,  8,1,  8,2,  9,0)
        DO4(v2, 13,1, 13,2, 14,0, 14,1)
        break;
    default:
        DO4(v0,  4,0,  4,1,  4,2,  5,0)
        DO4(v1,  9,1,  9,2, 10,0, 10,1)
        DO4(v2, 14,2, 15,0, 15,1, 15,2)
        break;
    }
    s0o = s0; s1o = s1; s2o = s2;
}

__global__ __launch_bounds__(256, 8) void sh_embed_coop2(
    const int* __restrict__ ys, const int* __restrict__ xs,
    const float* __restrict__ dirs, const float* __restrict__ sh,
    float* __restrict__ out, int B)
{
    // [wave][chunk-set j][lane*4 floats]: 4 * 3 * 256 * 4B = 12 KiB
    __shared__ float lds[4][3][256];

    const int tid  = threadIdx.x;
    const int gid  = blockIdx.x * 256 + tid;
    const int q    = tid & 3;
    const int half = (B + 1) >> 1;
    const int rayA = gid >> 2;
    if (rayA >= half) return;
    const int  rayB = rayA + half;
    const bool hasB = (rayB < B);

    // ---- issue ALL index/dir loads up front (streamed, coalesced) ----
    const int yA = ys[rayA];
    const int xA = xs[rayA];
    int yB = 0, xB = 0;
    if (hasB) { yB = ys[rayB]; xB = xs[rayB]; }

    const float dA0 = dirs[3 * rayA + 0];
    const float dA1 = dirs[3 * rayA + 1];
    const float dA2 = dirs[3 * rayA + 2];
    float dB0 = 0.f, dB1 = 0.f, dB2 = 0.f;
    if (hasB) { dB0 = dirs[3 * rayB + 0]; dB1 = dirs[3 * rayB + 1]; dB2 = dirs[3 * rayB + 2]; }

    // ---- ray A gather -> VGPRs (3 x 16B, 4-lane coalesced into 64B lines) ----
    const float4* __restrict__ c4A =
        (const float4*)(sh + (size_t)(yA * 1024 + xA) * 48u);
    const float4 vA0 = c4A[q];
    const float4 vA1 = c4A[q + 4];
    const float4 vA2 = c4A[q + 8];

    // ---- ray B gather -> LDS (3 x 16B per lane, vmcnt-tracked, zero VGPR) ----
    const int wave = tid >> 6;
    const int lane = tid & 63;
    if (hasB) {
        const float* gB = sh + (size_t)(yB * 1024 + xB) * 48u + 4 * q;
        __builtin_amdgcn_global_load_lds(
            (const __attribute__((address_space(1))) void*)(gB),
            (__attribute__((address_space(3))) void*)&lds[wave][0][4 * lane], 16, 0, 0);
        __builtin_amdgcn_global_load_lds(
            (const __attribute__((address_space(1))) void*)(gB + 16),
            (__attribute__((address_space(3))) void*)&lds[wave][1][4 * lane], 16, 0, 0);
        __builtin_amdgcn_global_load_lds(
            (const __attribute__((address_space(1))) void*)(gB + 32),
            (__attribute__((address_space(3))) void*)&lds[wave][2][4 * lane], 16, 0, 0);
    }

    // ---- compute ray A while B's loads fly ----
    float b[16];
    sh_basis(dA0, dA1, dA2, b);

    float s0, s1, s2;
    sh_accum(q, b, vA0, vA1, vA2, s0, s1, s2);

    s0 += __shfl_xor(s0, 1, 64);  s0 += __shfl_xor(s0, 2, 64);
    s1 += __shfl_xor(s1, 1, 64);  s1 += __shfl_xor(s1, 2, 64);
    s2 += __shfl_xor(s2, 1, 64);  s2 += __shfl_xor(s2, 2, 64);

    if (q < 3) {
        float val = (q == 0) ? s0 : (q == 1) ? s1 : s2;
        out[(size_t)3 * rayA + q] = fminf(fmaxf(val, 0.0f), 1.0f);
    }

    // ---- ray B: drain its LDS gathers (same wave wrote them -> no barrier) ----
    if (hasB) {
        asm volatile("s_waitcnt vmcnt(0)" ::: "memory");
        __builtin_amdgcn_sched_barrier(0);

        const float4 vB0 = *(const float4*)&lds[wave][0][4 * lane];
        const float4 vB1 = *(const float4*)&lds[wave][1][4 * lane];
        const float4 vB2 = *(const float4*)&lds[wave][2][4 * lane];

        sh_basis(dB0, dB1, dB2, b);
        sh_accum(q, b, vB0, vB1, vB2, s0, s1, s2);

        s0 += __shfl_xor(s0, 1, 64);  s0 += __shfl_xor(s0, 2, 64);
        s1 += __shfl_xor(s1, 1, 64);  s1 += __shfl_xor(s1, 2, 64);
        s2 += __shfl_xor(s2, 1, 64);  s2 += __shfl_xor(s2, 2, 64);

        if (q < 3) {
            float val = (q == 0) ? s0 : (q == 1) ? s1 : s2;
            out[(size_t)3 * rayB + q] = fminf(fmaxf(val, 0.0f), 1.0f);
        }
    }
}

extern "C" void kernel_launch(void* const* d_in, const int* in_sizes, int n_in,
                              void* d_out, int out_size, void* d_ws, size_t ws_size,
                              hipStream_t stream) {
    const int*   ys   = (const int*)d_in[0];
    const int*   xs   = (const int*)d_in[1];
    const float* dirs = (const float*)d_in[2];
    const float* sh   = (const float*)d_in[3];
    float* out = (float*)d_out;
    int B = in_sizes[0];
    // 4 threads per A-ray, 2 rays per thread -> 128 rays per 256-thread block.
    int half   = (B + 1) >> 1;
    int blocks = (half + 63) / 64;
    sh_embed_coop2<<<blocks, 256, 0, stream>>>(ys, xs, dirs, sh, out, B);
}